// Round 2
// baseline (4552.541 us; speedup 1.0000x reference)
//
#include <hip/hip_runtime.h>
#include <hip/hip_fp16.h>
#include <hip/hip_cooperative_groups.h>

namespace cg = cooperative_groups;

#define TS 40
#define NB 2048
#define NU 1024
#define NI 1024
#define ND 2048
#define UD (1024 * 2048)  // elems in one W_t  [u][2048]

typedef _Float16 half8 __attribute__((ext_vector_type(8)));
typedef _Float16 half4v __attribute__((ext_vector_type(4)));
typedef float floatx4 __attribute__((ext_vector_type(4)));

__device__ __forceinline__ float tanh_fast(float v) {
  float e = __expf(2.0f * v);
  return 1.0f - 2.0f / (e + 1.0f);  // inf-safe
}

// ---------------- W prep: W[t][u][k] = sum_q Qw[k][u*8+q]*Bt[t][q] (f16) ----
__global__ __launch_bounds__(256) void wprep(
    const float* __restrict__ Qw, const float* __restrict__ Bt,
    _Float16* __restrict__ W, int t0, int nt)
{
  __shared__ float ldsQ[32 * 257];
  __shared__ float ldsB[TS * 8];
  const int tid = threadIdx.x;
  const int k0 = blockIdx.x * 32;
  const int u0 = blockIdx.y * 32;
  for (int i = tid; i < TS * 8; i += 256) ldsB[i] = Bt[i];
  const float* qbase = Qw + (size_t)k0 * 8192 + (size_t)u0 * 8;
#pragma unroll
  for (int i = 0; i < 8; ++i) {
    int s = i * 256 + tid;
    int r = s >> 6, c4 = s & 63;
    float4 v = *(const float4*)(qbase + (size_t)r * 8192 + c4 * 4);
    float* d = &ldsQ[r * 257 + c4 * 4];
    d[0] = v.x; d[1] = v.y; d[2] = v.z; d[3] = v.w;
  }
  __syncthreads();
  const int kl = tid & 31;
  const int ug = tid >> 5;
#pragma unroll
  for (int p = 0; p < 4; ++p) {
    int uu = p * 8 + ug;
    float q[8];
#pragma unroll
    for (int j = 0; j < 8; ++j) q[j] = ldsQ[kl * 257 + uu * 8 + j];
    size_t obase = (size_t)(u0 + uu) * 2048 + k0 + kl;
    for (int tt = 0; tt < nt; ++tt) {
      const float* bt = &ldsB[(t0 + tt) * 8];
      float v = 0.f;
#pragma unroll
      for (int j = 0; j < 8; ++j) v += q[j] * bt[j];
      W[(size_t)tt * UD + obase] = (_Float16)v;
    }
  }
}

// ---------------- h0 fp32 -> f16 --------------------------------------------
__global__ __launch_bounds__(256) void hinit(const float* __restrict__ h0,
                                             _Float16* __restrict__ hb) {
  size_t i = (size_t)blockIdx.x * 256 + threadIdx.x;
  float4 v = *(const float4*)(h0 + i * 4);
  half4v h;
  h[0] = (_Float16)v.x; h[1] = (_Float16)v.y;
  h[2] = (_Float16)v.z; h[3] = (_Float16)v.w;
  *(half4v*)(hb + i * 4) = h;
}

// ---------------- batched x-projection: pre[t][b][u] = x_t @ Wx_t + bias ----
// 128x128 tile, BK=64, grid (16,8,40), 4 waves each 64x64.
__global__ __launch_bounds__(256) void xproj(
    const float* __restrict__ x, const _Float16* __restrict__ W,
    const float* __restrict__ bias, float* __restrict__ pre)
{
  __shared__ _Float16 ldsA[2][128 * 64];
  __shared__ _Float16 ldsB[2][128 * 64];
  const int tid = threadIdx.x;
  const int t = blockIdx.z;
  const int b0 = blockIdx.x * 128;
  const int u0 = blockIdx.y * 128;
  const int lane = tid & 63;
  const int wv = tid >> 6;
  const int wm = wv >> 1, wn = wv & 1;
  const int l15 = lane & 15, lk = lane >> 4;

  float4 areg[8];
  uint4 breg[4];
  const float* xb = x + (size_t)b0 * (TS * NI) + (size_t)t * NI;
  const _Float16* wb = W + (size_t)t * UD + (size_t)u0 * ND + NU;  // x-half of K

  auto stage_load = [&](int kt) {
    const int k0 = kt * 64;
#pragma unroll
    for (int i = 0; i < 8; ++i) {
      int s = i * 256 + tid;
      int r = s >> 4, c4 = s & 15;
      areg[i] = *(const float4*)(xb + (size_t)r * (TS * NI) + k0 + c4 * 4);
    }
#pragma unroll
    for (int i = 0; i < 4; ++i) {
      int s = i * 256 + tid;
      int u = s >> 3, c8 = s & 7;
      breg[i] = *(const uint4*)(wb + (size_t)u * ND + k0 + c8 * 8);
    }
  };

  auto stage_write = [&](int buf) {
    char* pA = (char*)&ldsA[buf][0];
    char* pB = (char*)&ldsB[buf][0];
#pragma unroll
    for (int i = 0; i < 8; ++i) {
      int s = i * 256 + tid;
      int r = s >> 4, c4 = s & 15;
      half4v h;
      h[0] = (_Float16)areg[i].x; h[1] = (_Float16)areg[i].y;
      h[2] = (_Float16)areg[i].z; h[3] = (_Float16)areg[i].w;
      int off = (r * 128 + c4 * 8) ^ ((r & 7) << 4);
      *(half4v*)(pA + off) = h;
    }
#pragma unroll
    for (int i = 0; i < 4; ++i) {
      int s = i * 256 + tid;
      int u = s >> 3, c8 = s & 7;
      int off = (u * 128 + c8 * 16) ^ ((u & 7) << 4);
      *(uint4*)(pB + off) = breg[i];
    }
  };

  floatx4 acc[4][4] = {};

  auto compute = [&](int buf) {
    const char* pA = (const char*)&ldsA[buf][0];
    const char* pB = (const char*)&ldsB[buf][0];
#pragma unroll
    for (int kk = 0; kk < 2; ++kk) {
      half8 af[4], bf[4];
#pragma unroll
      for (int mf = 0; mf < 4; ++mf) {
        int r = wm * 64 + mf * 16 + l15;
        int off = r * 128 + ((((kk << 2) | lk) ^ (r & 7)) << 4);
        af[mf] = *(const half8*)(pA + off);
      }
#pragma unroll
      for (int nf = 0; nf < 4; ++nf) {
        int u = wn * 64 + nf * 16 + l15;
        int off = u * 128 + ((((kk << 2) | lk) ^ (u & 7)) << 4);
        bf[nf] = *(const half8*)(pB + off);
      }
#pragma unroll
      for (int mf = 0; mf < 4; ++mf)
#pragma unroll
        for (int nf = 0; nf < 4; ++nf)
          acc[mf][nf] =
              __builtin_amdgcn_mfma_f32_16x16x32_f16(af[mf], bf[nf], acc[mf][nf], 0, 0, 0);
    }
  };

  stage_load(0);
  stage_write(0);
  __syncthreads();
#pragma unroll 1
  for (int kt = 0; kt < 16; ++kt) {
    int cur = kt & 1;
    if (kt + 1 < 16) stage_load(kt + 1);
    compute(cur);
    if (kt + 1 < 16) stage_write(cur ^ 1);
    __syncthreads();
  }

#pragma unroll
  for (int mf = 0; mf < 4; ++mf)
#pragma unroll
    for (int nf = 0; nf < 4; ++nf) {
      int u = u0 + wn * 64 + nf * 16 + l15;
      float bv = bias[u];
      int brow = b0 + wm * 64 + mf * 16 + (lk << 2);
#pragma unroll
      for (int j = 0; j < 4; ++j)
        pre[((size_t)t * NB + brow + j) * NU + u] = acc[mf][nf][j] + bv;
    }
}

// ---------------- serial chain: h_t = tanh(h_{t-1} @ Wh_t + pre_t) ----------
// 64x128 tile, K=1024 (16 x BK=64). COOP: all 40 steps, grid.sync between.
template <bool COOP>
__global__ __launch_bounds__(256) void serial_steps(
    const _Float16* __restrict__ W, const float* __restrict__ pre,
    _Float16* __restrict__ hbuf, float* __restrict__ out, int t0, int t1)
{
  __shared__ _Float16 ldsA[2][64 * 64];
  __shared__ _Float16 ldsB[2][128 * 64];
  const int tid = threadIdx.x;
  const int bid = blockIdx.x;
  // b-tiles grouped per XCD: xcd = bid&7 hosts b-tiles 4*xcd..4*xcd+3, all u.
  const int btile = (bid & 7) * 4 + ((bid >> 3) & 3);
  const int b0 = btile * 64;
  const int u0 = (bid >> 5) * 128;
  const int lane = tid & 63;
  const int wv = tid >> 6;
  const int wm = wv >> 1, wn = wv & 1;
  const int l15 = lane & 15, lk = lane >> 4;

#pragma unroll 1
  for (int t = t0; t < t1; ++t) {
    const _Float16* Ab = hbuf + (size_t)(t & 1) * ((size_t)NB * NU);
    const _Float16* Wb = W + (size_t)t * UD + (size_t)u0 * ND;
    uint4 areg[2], breg[4];

    auto stage_load = [&](int kt) {
      const int k0 = kt * 64;
#pragma unroll
      for (int i = 0; i < 2; ++i) {
        int s = i * 256 + tid;
        int r = s >> 3, g = s & 7;
        areg[i] = *(const uint4*)(Ab + (size_t)(b0 + r) * NU + k0 + g * 8);
      }
#pragma unroll
      for (int i = 0; i < 4; ++i) {
        int s = i * 256 + tid;
        int u = s >> 3, c8 = s & 7;
        breg[i] = *(const uint4*)(Wb + (size_t)u * ND + k0 + c8 * 8);
      }
    };

    auto stage_write = [&](int buf) {
      char* pA = (char*)&ldsA[buf][0];
      char* pB = (char*)&ldsB[buf][0];
#pragma unroll
      for (int i = 0; i < 2; ++i) {
        int s = i * 256 + tid;
        int r = s >> 3, g = s & 7;
        int off = (r * 128 + g * 16) ^ ((r & 7) << 4);
        *(uint4*)(pA + off) = areg[i];
      }
#pragma unroll
      for (int i = 0; i < 4; ++i) {
        int s = i * 256 + tid;
        int u = s >> 3, c8 = s & 7;
        int off = (u * 128 + c8 * 16) ^ ((u & 7) << 4);
        *(uint4*)(pB + off) = breg[i];
      }
    };

    floatx4 acc[2][4] = {};

    auto compute = [&](int buf) {
      const char* pA = (const char*)&ldsA[buf][0];
      const char* pB = (const char*)&ldsB[buf][0];
#pragma unroll
      for (int kk = 0; kk < 2; ++kk) {
        half8 af[2], bf[4];
#pragma unroll
        for (int mf = 0; mf < 2; ++mf) {
          int r = wm * 32 + mf * 16 + l15;
          int off = r * 128 + ((((kk << 2) | lk) ^ (r & 7)) << 4);
          af[mf] = *(const half8*)(pA + off);
        }
#pragma unroll
        for (int nf = 0; nf < 4; ++nf) {
          int u = wn * 64 + nf * 16 + l15;
          int off = u * 128 + ((((kk << 2) | lk) ^ (u & 7)) << 4);
          bf[nf] = *(const half8*)(pB + off);
        }
#pragma unroll
        for (int mf = 0; mf < 2; ++mf)
#pragma unroll
          for (int nf = 0; nf < 4; ++nf)
            acc[mf][nf] =
                __builtin_amdgcn_mfma_f32_16x16x32_f16(af[mf], bf[nf], acc[mf][nf], 0, 0, 0);
      }
    };

    stage_load(0);
    stage_write(0);
    __syncthreads();
#pragma unroll 1
    for (int kt = 0; kt < 16; ++kt) {
      int cur = kt & 1;
      if (kt + 1 < 16) stage_load(kt + 1);
      compute(cur);
      if (kt + 1 < 16) stage_write(cur ^ 1);
      __syncthreads();
    }

    _Float16* hn = hbuf + (size_t)((t + 1) & 1) * ((size_t)NB * NU);
#pragma unroll
    for (int mf = 0; mf < 2; ++mf)
#pragma unroll
      for (int nf = 0; nf < 4; ++nf) {
        int u = u0 + wn * 64 + nf * 16 + l15;
        int brow = b0 + wm * 32 + mf * 16 + (lk << 2);
#pragma unroll
        for (int j = 0; j < 4; ++j) {
          float p = pre[((size_t)t * NB + brow + j) * NU + u];
          float v = tanh_fast(acc[mf][nf][j] + p);
          out[((size_t)(brow + j) * TS + t) * NU + u] = v;
          hn[(size_t)(brow + j) * NU + u] = (_Float16)v;
        }
      }

    if constexpr (COOP) {
      __threadfence();
      cg::this_grid().sync();
    }
  }
}

// ---------------- round-1 fallback step GEMM (K=2048, fused cat) ------------
__global__ __launch_bounds__(256) void step_gemm(
    const float* __restrict__ xt, const float* __restrict__ hp, long hstride,
    const _Float16* __restrict__ Wt, const float* __restrict__ bias,
    float* __restrict__ outt)
{
  __shared__ _Float16 ldsA[2][64 * 64];
  __shared__ _Float16 ldsB[2][128 * 64];
  const int tid = threadIdx.x;
  const int b0 = blockIdx.x * 64;
  const int u0 = blockIdx.y * 128;
  const int lane = tid & 63;
  const int wv = tid >> 6;
  const int wm = wv >> 1, wn = wv & 1;
  const int l15 = lane & 15, lk = lane >> 4;

  float4 areg[4];
  uint4 breg[4];

  auto stage_load = [&](int kt) {
    const int k0 = kt * 64;
    const float* src; size_t stride; int koff;
    if (k0 < NU) { src = hp; stride = (size_t)hstride; koff = k0; }
    else { src = xt; stride = (size_t)TS * NI; koff = k0 - NU; }
#pragma unroll
    for (int i = 0; i < 4; ++i) {
      int s = i * 256 + tid;
      int r = s >> 4, c4 = s & 15;
      areg[i] = *(const float4*)(src + (size_t)(b0 + r) * stride + koff + c4 * 4);
    }
    const _Float16* wsrc = Wt + (size_t)u0 * 2048 + k0;
#pragma unroll
    for (int i = 0; i < 4; ++i) {
      int s = i * 256 + tid;
      int u = s >> 3, c8 = s & 7;
      breg[i] = *(const uint4*)(wsrc + (size_t)u * 2048 + c8 * 8);
    }
  };

  auto stage_write = [&](int buf) {
    char* pA = (char*)&ldsA[buf][0];
    char* pB = (char*)&ldsB[buf][0];
#pragma unroll
    for (int i = 0; i < 4; ++i) {
      int s = i * 256 + tid;
      int r = s >> 4, c4 = s & 15;
      half4v h;
      h[0] = (_Float16)areg[i].x; h[1] = (_Float16)areg[i].y;
      h[2] = (_Float16)areg[i].z; h[3] = (_Float16)areg[i].w;
      int off = (r * 128 + c4 * 8) ^ ((r & 7) << 4);
      *(half4v*)(pA + off) = h;
    }
#pragma unroll
    for (int i = 0; i < 4; ++i) {
      int s = i * 256 + tid;
      int u = s >> 3, c8 = s & 7;
      int off = (u * 128 + c8 * 16) ^ ((u & 7) << 4);
      *(uint4*)(pB + off) = breg[i];
    }
  };

  floatx4 acc[2][4] = {};

  auto compute = [&](int buf) {
    const char* pA = (const char*)&ldsA[buf][0];
    const char* pB = (const char*)&ldsB[buf][0];
#pragma unroll
    for (int kk = 0; kk < 2; ++kk) {
      half8 af[2], bf[4];
#pragma unroll
      for (int mf = 0; mf < 2; ++mf) {
        int r = wm * 32 + mf * 16 + l15;
        int off = r * 128 + ((((kk << 2) | lk) ^ (r & 7)) << 4);
        af[mf] = *(const half8*)(pA + off);
      }
#pragma unroll
      for (int nf = 0; nf < 4; ++nf) {
        int u = wn * 64 + nf * 16 + l15;
        int off = u * 128 + ((((kk << 2) | lk) ^ (u & 7)) << 4);
        bf[nf] = *(const half8*)(pB + off);
      }
#pragma unroll
      for (int mf = 0; mf < 2; ++mf)
#pragma unroll
        for (int nf = 0; nf < 4; ++nf)
          acc[mf][nf] =
              __builtin_amdgcn_mfma_f32_16x16x32_f16(af[mf], bf[nf], acc[mf][nf], 0, 0, 0);
    }
  };

  stage_load(0);
  stage_write(0);
  __syncthreads();
#pragma unroll 1
  for (int kt = 0; kt < 32; ++kt) {
    int cur = kt & 1;
    if (kt + 1 < 32) stage_load(kt + 1);
    compute(cur);
    if (kt + 1 < 32) stage_write(cur ^ 1);
    __syncthreads();
  }

#pragma unroll
  for (int mf = 0; mf < 2; ++mf)
#pragma unroll
    for (int nf = 0; nf < 4; ++nf) {
      int u = u0 + wn * 64 + nf * 16 + l15;
      float bv = bias[u];
      int brow = b0 + wm * 32 + mf * 16 + (lk << 2);
#pragma unroll
      for (int j = 0; j < 4; ++j) {
        float prev = acc[mf][nf][j] + bv;
        outt[(size_t)(brow + j) * (TS * NU) + u] = tanh_fast(prev);
      }
    }
}

extern "C" void kernel_launch(void* const* d_in, const int* in_sizes, int n_in,
                              void* d_out, int out_size, void* d_ws, size_t ws_size,
                              hipStream_t stream) {
  const float* x    = (const float*)d_in[0];
  const float* h0   = (const float*)d_in[1];
  const float* Qw   = (const float*)d_in[2];
  const float* bias = (const float*)d_in[3];
  const float* Bt   = (const float*)d_in[4];
  float* out = (float*)d_out;

  char* ws = (char*)d_ws;
  const size_t w_bytes   = (size_t)UD * TS * sizeof(_Float16);       // 167.8 MB
  const size_t pre_bytes = (size_t)TS * NB * NU * sizeof(float);     // 335.5 MB
  const size_t h_bytes   = (size_t)2 * NB * NU * sizeof(_Float16);   // 8.4 MB
  const size_t need = w_bytes + pre_bytes + h_bytes;                 // 511.7 MB

  _Float16* W = (_Float16*)ws;

  if (ws_size >= need) {
    float* pre = (float*)(ws + w_bytes);
    _Float16* hbuf = (_Float16*)(ws + w_bytes + pre_bytes);

    wprep<<<dim3(64, 32), 256, 0, stream>>>(Qw, Bt, W, 0, TS);
    hinit<<<dim3((NB * NU) / (256 * 4)), 256, 0, stream>>>(h0, hbuf);
    xproj<<<dim3(16, 8, TS), 256, 0, stream>>>(x, W, bias, pre);

    const _Float16* Wa = W;
    const float* prea = pre;
    _Float16* hba = hbuf;
    float* outa = out;
    int t0 = 0, t1 = TS;
    void* args[6] = {(void*)&Wa, (void*)&prea, (void*)&hba, (void*)&outa,
                     (void*)&t0, (void*)&t1};
    hipError_t e = hipLaunchCooperativeKernel(
        (const void*)serial_steps<true>, dim3(256), dim3(256), args, 0, stream);
    if (e != hipSuccess) {
      for (int t = 0; t < TS; ++t)
        serial_steps<false><<<dim3(256), 256, 0, stream>>>(W, pre, hbuf, out, t, t + 1);
    }
  } else {
    // round-1 fallback
    const bool big = ws_size >= w_bytes;
    if (big) wprep<<<dim3(64, 32), 256, 0, stream>>>(Qw, Bt, W, 0, TS);
    for (int t = 0; t < TS; ++t) {
      const _Float16* Wtp;
      if (big) {
        Wtp = W + (size_t)t * UD;
      } else {
        wprep<<<dim3(64, 32), 256, 0, stream>>>(Qw, Bt, W, t, 1);
        Wtp = W;
      }
      const float* hp = (t == 0) ? h0 : out + (size_t)(t - 1) * NU;
      long hstride = (t == 0) ? NU : (long)TS * NU;
      step_gemm<<<dim3(32, 8), 256, 0, stream>>>(
          x + (size_t)t * NI, hp, hstride, Wtp, bias, out + (size_t)t * NU);
    }
  }
}

// Round 3
// 2123.022 us; speedup vs baseline: 2.1444x; 2.1444x over previous
//
#include <hip/hip_runtime.h>
#include <hip/hip_fp16.h>

#define TS 40
#define NB 2048
#define NU 1024
#define NI 1024
#define ND 2048
#define UD (1024 * 2048)  // elems in one W_t  [u][2048]

typedef _Float16 half8 __attribute__((ext_vector_type(8)));
typedef _Float16 half4v __attribute__((ext_vector_type(4)));
typedef float floatx4 __attribute__((ext_vector_type(4)));

__device__ __forceinline__ float tanh_fast(float v) {
  float e = __expf(2.0f * v);
  return 1.0f - 2.0f / (e + 1.0f);  // inf-safe
}

// ---------------- W prep: W[t][u][k] = sum_q Qw[k][u*8+q]*Bt[t][q] (f16) ----
__global__ __launch_bounds__(256) void wprep(
    const float* __restrict__ Qw, const float* __restrict__ Bt,
    _Float16* __restrict__ W, int t0, int nt)
{
  __shared__ float ldsQ[32 * 257];
  __shared__ float ldsB[TS * 8];
  const int tid = threadIdx.x;
  const int k0 = blockIdx.x * 32;
  const int u0 = blockIdx.y * 32;
  for (int i = tid; i < TS * 8; i += 256) ldsB[i] = Bt[i];
  const float* qbase = Qw + (size_t)k0 * 8192 + (size_t)u0 * 8;
#pragma unroll
  for (int i = 0; i < 8; ++i) {
    int s = i * 256 + tid;
    int r = s >> 6, c4 = s & 63;
    float4 v = *(const float4*)(qbase + (size_t)r * 8192 + c4 * 4);
    float* d = &ldsQ[r * 257 + c4 * 4];
    d[0] = v.x; d[1] = v.y; d[2] = v.z; d[3] = v.w;
  }
  __syncthreads();
  const int kl = tid & 31;
  const int ug = tid >> 5;
#pragma unroll
  for (int p = 0; p < 4; ++p) {
    int uu = p * 8 + ug;
    float q[8];
#pragma unroll
    for (int j = 0; j < 8; ++j) q[j] = ldsQ[kl * 257 + uu * 8 + j];
    size_t obase = (size_t)(u0 + uu) * 2048 + k0 + kl;
    for (int tt = 0; tt < nt; ++tt) {
      const float* bt = &ldsB[(t0 + tt) * 8];
      float v = 0.f;
#pragma unroll
      for (int j = 0; j < 8; ++j) v += q[j] * bt[j];
      W[(size_t)tt * UD + obase] = (_Float16)v;
    }
  }
}

// ---------------- h0 fp32 -> f16 --------------------------------------------
__global__ __launch_bounds__(256) void hinit(const float* __restrict__ h0,
                                             _Float16* __restrict__ hb) {
  size_t i = (size_t)blockIdx.x * 256 + threadIdx.x;
  float4 v = *(const float4*)(h0 + i * 4);
  half4v h;
  h[0] = (_Float16)v.x; h[1] = (_Float16)v.y;
  h[2] = (_Float16)v.z; h[3] = (_Float16)v.w;
  *(half4v*)(hb + i * 4) = h;
}

// ---------------- batched x-projection: pre[t][b][u] = x_t @ Wx_t + bias ----
// 128x128 tile, BK=64, grid (16,8,40), 4 waves each 64x64. pre in f16.
__global__ __launch_bounds__(256) void xproj(
    const float* __restrict__ x, const _Float16* __restrict__ W,
    const float* __restrict__ bias, _Float16* __restrict__ pre)
{
  __shared__ _Float16 ldsA[2][128 * 64];
  __shared__ _Float16 ldsB[2][128 * 64];
  const int tid = threadIdx.x;
  const int t = blockIdx.z;
  const int b0 = blockIdx.x * 128;
  const int u0 = blockIdx.y * 128;
  const int lane = tid & 63;
  const int wv = tid >> 6;
  const int wm = wv >> 1, wn = wv & 1;
  const int l15 = lane & 15, lk = lane >> 4;

  float4 areg[8];
  uint4 breg[4];
  const float* xb = x + (size_t)b0 * (TS * NI) + (size_t)t * NI;
  const _Float16* wb = W + (size_t)t * UD + (size_t)u0 * ND + NU;  // x-half of K

  auto stage_load = [&](int kt) {
    const int k0 = kt * 64;
#pragma unroll
    for (int i = 0; i < 8; ++i) {
      int s = i * 256 + tid;
      int r = s >> 4, c4 = s & 15;
      areg[i] = *(const float4*)(xb + (size_t)r * (TS * NI) + k0 + c4 * 4);
    }
#pragma unroll
    for (int i = 0; i < 4; ++i) {
      int s = i * 256 + tid;
      int u = s >> 3, c8 = s & 7;
      breg[i] = *(const uint4*)(wb + (size_t)u * ND + k0 + c8 * 8);
    }
  };

  auto stage_write = [&](int buf) {
    char* pA = (char*)&ldsA[buf][0];
    char* pB = (char*)&ldsB[buf][0];
#pragma unroll
    for (int i = 0; i < 8; ++i) {
      int s = i * 256 + tid;
      int r = s >> 4, c4 = s & 15;
      half4v h;
      h[0] = (_Float16)areg[i].x; h[1] = (_Float16)areg[i].y;
      h[2] = (_Float16)areg[i].z; h[3] = (_Float16)areg[i].w;
      int off = (r * 128 + c4 * 8) ^ ((r & 7) << 4);
      *(half4v*)(pA + off) = h;
    }
#pragma unroll
    for (int i = 0; i < 4; ++i) {
      int s = i * 256 + tid;
      int u = s >> 3, c8 = s & 7;
      int off = (u * 128 + c8 * 16) ^ ((u & 7) << 4);
      *(uint4*)(pB + off) = breg[i];
    }
  };

  floatx4 acc[4][4] = {};

  auto compute = [&](int buf) {
    const char* pA = (const char*)&ldsA[buf][0];
    const char* pB = (const char*)&ldsB[buf][0];
#pragma unroll
    for (int kk = 0; kk < 2; ++kk) {
      half8 af[4], bf[4];
#pragma unroll
      for (int mf = 0; mf < 4; ++mf) {
        int r = wm * 64 + mf * 16 + l15;
        int off = r * 128 + ((((kk << 2) | lk) ^ (r & 7)) << 4);
        af[mf] = *(const half8*)(pA + off);
      }
#pragma unroll
      for (int nf = 0; nf < 4; ++nf) {
        int u = wn * 64 + nf * 16 + l15;
        int off = u * 128 + ((((kk << 2) | lk) ^ (u & 7)) << 4);
        bf[nf] = *(const half8*)(pB + off);
      }
#pragma unroll
      for (int mf = 0; mf < 4; ++mf)
#pragma unroll
        for (int nf = 0; nf < 4; ++nf)
          acc[mf][nf] =
              __builtin_amdgcn_mfma_f32_16x16x32_f16(af[mf], bf[nf], acc[mf][nf], 0, 0, 0);
    }
  };

  stage_load(0);
  stage_write(0);
  __syncthreads();
#pragma unroll 1
  for (int kt = 0; kt < 16; ++kt) {
    int cur = kt & 1;
    if (kt + 1 < 16) stage_load(kt + 1);
    compute(cur);
    if (kt + 1 < 16) stage_write(cur ^ 1);
    __syncthreads();
  }

#pragma unroll
  for (int mf = 0; mf < 4; ++mf)
#pragma unroll
    for (int nf = 0; nf < 4; ++nf) {
      int u = u0 + wn * 64 + nf * 16 + l15;
      float bv = bias[u];
      int brow = b0 + wm * 64 + mf * 16 + (lk << 2);
#pragma unroll
      for (int j = 0; j < 4; ++j)
        pre[((size_t)t * NB + brow + j) * NU + u] =
            (_Float16)(acc[mf][nf][j] + bv);
    }
}

// ---------------- serial step: h_t = tanh(h_{t-1} @ Wh_t + pre_t) -----------
// 64x64 tile, K=1024 (16 x BK=64). 512 blocks (2/CU), 4 waves of 32x32.
__global__ __launch_bounds__(256) void serial_step(
    const _Float16* __restrict__ Wt,    // W + t*UD  (use k in [0,1024))
    const _Float16* __restrict__ pret,  // pre + t*NB*NU
    const _Float16* __restrict__ hprev, // [NB][NU]
    _Float16* __restrict__ hnext,       // [NB][NU]
    float* __restrict__ outt)           // out + t*NU, row stride TS*NU
{
  __shared__ _Float16 ldsA[2][64 * 64];
  __shared__ _Float16 ldsB[2][64 * 64];
  const int tid = threadIdx.x;
  const int bid = blockIdx.x;
  const int b0 = (bid & 31) * 64;   // bid%8 = XCD -> 4 b-panels/XCD
  const int u0 = (bid >> 5) * 64;
  const int lane = tid & 63;
  const int wv = tid >> 6;
  const int wm = wv >> 1, wn = wv & 1;
  const int l15 = lane & 15, lk = lane >> 4;

  const _Float16* Wb = Wt + (size_t)u0 * ND;
  uint4 areg[2], breg[2];

  auto stage_load = [&](int kt) {
    const int k0 = kt * 64;
#pragma unroll
    for (int i = 0; i < 2; ++i) {
      int s = i * 256 + tid;
      int r = s >> 3, g = s & 7;
      areg[i] = *(const uint4*)(hprev + (size_t)(b0 + r) * NU + k0 + g * 8);
      breg[i] = *(const uint4*)(Wb + (size_t)r * ND + k0 + g * 8);
    }
  };

  auto stage_write = [&](int buf) {
    char* pA = (char*)&ldsA[buf][0];
    char* pB = (char*)&ldsB[buf][0];
#pragma unroll
    for (int i = 0; i < 2; ++i) {
      int s = i * 256 + tid;
      int r = s >> 3, g = s & 7;
      int off = (r * 128 + g * 16) ^ ((r & 7) << 4);
      *(uint4*)(pA + off) = areg[i];
      *(uint4*)(pB + off) = breg[i];
    }
  };

  floatx4 acc[2][2] = {};

  auto compute = [&](int buf) {
    const char* pA = (const char*)&ldsA[buf][0];
    const char* pB = (const char*)&ldsB[buf][0];
#pragma unroll
    for (int kk = 0; kk < 2; ++kk) {
      half8 af[2], bf[2];
#pragma unroll
      for (int mf = 0; mf < 2; ++mf) {
        int r = wm * 32 + mf * 16 + l15;
        int off = r * 128 + ((((kk << 2) | lk) ^ (r & 7)) << 4);
        af[mf] = *(const half8*)(pA + off);
      }
#pragma unroll
      for (int nf = 0; nf < 2; ++nf) {
        int u = wn * 32 + nf * 16 + l15;
        int off = u * 128 + ((((kk << 2) | lk) ^ (u & 7)) << 4);
        bf[nf] = *(const half8*)(pB + off);
      }
#pragma unroll
      for (int mf = 0; mf < 2; ++mf)
#pragma unroll
        for (int nf = 0; nf < 2; ++nf)
          acc[mf][nf] =
              __builtin_amdgcn_mfma_f32_16x16x32_f16(af[mf], bf[nf], acc[mf][nf], 0, 0, 0);
    }
  };

  stage_load(0);
  stage_write(0);
  __syncthreads();
#pragma unroll 1
  for (int kt = 0; kt < 16; ++kt) {
    int cur = kt & 1;
    if (kt + 1 < 16) stage_load(kt + 1);
    compute(cur);
    if (kt + 1 < 16) stage_write(cur ^ 1);
    __syncthreads();
  }

#pragma unroll
  for (int mf = 0; mf < 2; ++mf)
#pragma unroll
    for (int nf = 0; nf < 2; ++nf) {
      int u = u0 + wn * 32 + nf * 16 + l15;
      int brow = b0 + wm * 32 + mf * 16 + (lk << 2);
#pragma unroll
      for (int j = 0; j < 4; ++j) {
        float p = (float)pret[(size_t)(brow + j) * NU + u];
        float v = tanh_fast(acc[mf][nf][j] + p);
        outt[(size_t)(brow + j) * (TS * NU) + u] = v;
        hnext[(size_t)(brow + j) * NU + u] = (_Float16)v;
      }
    }
}

// ---------------- round-1 fallback step GEMM (K=2048, fused cat) ------------
__global__ __launch_bounds__(256) void step_gemm(
    const float* __restrict__ xt, const float* __restrict__ hp, long hstride,
    const _Float16* __restrict__ Wt, const float* __restrict__ bias,
    float* __restrict__ outt)
{
  __shared__ _Float16 ldsA[2][64 * 64];
  __shared__ _Float16 ldsB[2][128 * 64];
  const int tid = threadIdx.x;
  const int b0 = blockIdx.x * 64;
  const int u0 = blockIdx.y * 128;
  const int lane = tid & 63;
  const int wv = tid >> 6;
  const int wm = wv >> 1, wn = wv & 1;
  const int l15 = lane & 15, lk = lane >> 4;

  float4 areg[4];
  uint4 breg[4];

  auto stage_load = [&](int kt) {
    const int k0 = kt * 64;
    const float* src; size_t stride; int koff;
    if (k0 < NU) { src = hp; stride = (size_t)hstride; koff = k0; }
    else { src = xt; stride = (size_t)TS * NI; koff = k0 - NU; }
#pragma unroll
    for (int i = 0; i < 4; ++i) {
      int s = i * 256 + tid;
      int r = s >> 4, c4 = s & 15;
      areg[i] = *(const float4*)(src + (size_t)(b0 + r) * stride + koff + c4 * 4);
    }
    const _Float16* wsrc = Wt + (size_t)u0 * 2048 + k0;
#pragma unroll
    for (int i = 0; i < 4; ++i) {
      int s = i * 256 + tid;
      int u = s >> 3, c8 = s & 7;
      breg[i] = *(const uint4*)(wsrc + (size_t)u * 2048 + c8 * 8);
    }
  };

  auto stage_write = [&](int buf) {
    char* pA = (char*)&ldsA[buf][0];
    char* pB = (char*)&ldsB[buf][0];
#pragma unroll
    for (int i = 0; i < 4; ++i) {
      int s = i * 256 + tid;
      int r = s >> 4, c4 = s & 15;
      half4v h;
      h[0] = (_Float16)areg[i].x; h[1] = (_Float16)areg[i].y;
      h[2] = (_Float16)areg[i].z; h[3] = (_Float16)areg[i].w;
      int off = (r * 128 + c4 * 8) ^ ((r & 7) << 4);
      *(half4v*)(pA + off) = h;
    }
#pragma unroll
    for (int i = 0; i < 4; ++i) {
      int s = i * 256 + tid;
      int u = s >> 3, c8 = s & 7;
      int off = (u * 128 + c8 * 16) ^ ((u & 7) << 4);
      *(uint4*)(pB + off) = breg[i];
    }
  };

  floatx4 acc[2][4] = {};

  auto compute = [&](int buf) {
    const char* pA = (const char*)&ldsA[buf][0];
    const char* pB = (const char*)&ldsB[buf][0];
#pragma unroll
    for (int kk = 0; kk < 2; ++kk) {
      half8 af[2], bf[4];
#pragma unroll
      for (int mf = 0; mf < 2; ++mf) {
        int r = wm * 32 + mf * 16 + l15;
        int off = r * 128 + ((((kk << 2) | lk) ^ (r & 7)) << 4);
        af[mf] = *(const half8*)(pA + off);
      }
#pragma unroll
      for (int nf = 0; nf < 4; ++nf) {
        int u = wn * 64 + nf * 16 + l15;
        int off = u * 128 + ((((kk << 2) | lk) ^ (u & 7)) << 4);
        bf[nf] = *(const half8*)(pB + off);
      }
#pragma unroll
      for (int mf = 0; mf < 2; ++mf)
#pragma unroll
        for (int nf = 0; nf < 4; ++nf)
          acc[mf][nf] =
              __builtin_amdgcn_mfma_f32_16x16x32_f16(af[mf], bf[nf], acc[mf][nf], 0, 0, 0);
    }
  };

  stage_load(0);
  stage_write(0);
  __syncthreads();
#pragma unroll 1
  for (int kt = 0; kt < 32; ++kt) {
    int cur = kt & 1;
    if (kt + 1 < 32) stage_load(kt + 1);
    compute(cur);
    if (kt + 1 < 32) stage_write(cur ^ 1);
    __syncthreads();
  }

#pragma unroll
  for (int mf = 0; mf < 2; ++mf)
#pragma unroll
    for (int nf = 0; nf < 4; ++nf) {
      int u = u0 + wn * 64 + nf * 16 + l15;
      float bv = bias[u];
      int brow = b0 + wm * 32 + mf * 16 + (lk << 2);
#pragma unroll
      for (int j = 0; j < 4; ++j) {
        float prev = acc[mf][nf][j] + bv;
        outt[(size_t)(brow + j) * (TS * NU) + u] = tanh_fast(prev);
      }
    }
}

extern "C" void kernel_launch(void* const* d_in, const int* in_sizes, int n_in,
                              void* d_out, int out_size, void* d_ws, size_t ws_size,
                              hipStream_t stream) {
  const float* x    = (const float*)d_in[0];
  const float* h0   = (const float*)d_in[1];
  const float* Qw   = (const float*)d_in[2];
  const float* bias = (const float*)d_in[3];
  const float* Bt   = (const float*)d_in[4];
  float* out = (float*)d_out;

  char* ws = (char*)d_ws;
  const size_t w_bytes   = (size_t)UD * TS * sizeof(_Float16);        // 167.8 MB
  const size_t pre_bytes = (size_t)TS * NB * NU * sizeof(_Float16);   // 167.8 MB
  const size_t h_bytes   = (size_t)2 * NB * NU * sizeof(_Float16);    // 8.4 MB
  const size_t need = w_bytes + pre_bytes + h_bytes;                  // ~344 MB

  _Float16* W = (_Float16*)ws;

  if (ws_size >= need) {
    _Float16* pre  = (_Float16*)(ws + w_bytes);
    _Float16* hbuf = (_Float16*)(ws + w_bytes + pre_bytes);

    wprep<<<dim3(64, 32), 256, 0, stream>>>(Qw, Bt, W, 0, TS);
    hinit<<<dim3((NB * NU) / (256 * 4)), 256, 0, stream>>>(h0, hbuf);
    xproj<<<dim3(16, 8, TS), 256, 0, stream>>>(x, W, bias, pre);

    for (int t = 0; t < TS; ++t) {
      const _Float16* hprev = hbuf + (size_t)(t & 1) * ((size_t)NB * NU);
      _Float16* hnext = hbuf + (size_t)((t + 1) & 1) * ((size_t)NB * NU);
      serial_step<<<dim3(512), 256, 0, stream>>>(
          W + (size_t)t * UD, pre + (size_t)t * NB * NU, hprev, hnext,
          out + (size_t)t * NU);
    }
  } else {
    // round-1 fallback
    const bool big = ws_size >= w_bytes;
    if (big) wprep<<<dim3(64, 32), 256, 0, stream>>>(Qw, Bt, W, 0, TS);
    for (int t = 0; t < TS; ++t) {
      const _Float16* Wtp;
      if (big) {
        Wtp = W + (size_t)t * UD;
      } else {
        wprep<<<dim3(64, 32), 256, 0, stream>>>(Qw, Bt, W, t, 1);
        Wtp = W;
      }
      const float* hp = (t == 0) ? h0 : out + (size_t)(t - 1) * NU;
      long hstride = (t == 0) ? NU : (long)TS * NU;
      step_gemm<<<dim3(32, 8), 256, 0, stream>>>(
          x + (size_t)t * NI, hp, hstride, Wtp, bias, out + (size_t)t * NU);
    }
  }
}

// Round 5
// 1173.960 us; speedup vs baseline: 3.8779x; 1.8084x over previous
//
#include <hip/hip_runtime.h>
#include <hip/hip_fp16.h>

#define TS 40
#define NB 2048
#define NU 1024
#define NI 1024
#define ND 2048
#define UD (1024 * 2048)  // elems in one W_t (4 MB as f16)

typedef _Float16 half8 __attribute__((ext_vector_type(8)));
typedef _Float16 half4v __attribute__((ext_vector_type(4)));
typedef float floatx4 __attribute__((ext_vector_type(4)));

__device__ __forceinline__ float tanh_fast(float v) {
  float e = __expf(2.0f * v);
  return 1.0f - 2.0f / (e + 1.0f);  // inf-safe
}

// async global->LDS, 16B per lane
__device__ __forceinline__ void gload16(const void* g, void* l) {
  __builtin_amdgcn_global_load_lds(
      (const __attribute__((address_space(1))) void*)g,
      (__attribute__((address_space(3))) void*)l, 16, 0, 0);
}

// ===== tiled-swizzled layout ================================================
// tile = 64 rows x 64 cols f16 = 8192 B. Within tile, value (r, c) lives at
// byte ((r*128 + (c>>3)*16) ^ ((r&7)<<4)) + (c&7)*2  -- i.e. the LDS XOR
// swizzle is pre-applied in global memory so tiles DMA linearly.
// W_tiled: [t][ut 0..15][kt 0..31][8192B]   (kt<16: h-part, kt>=16: x-part)
// h_tiled: [bt 0..31][kt 0..15][8192B]

// ---------------- wprep: Qw (fp32) -> W tiled-swizzled f16 ------------------
// block (kt, ut) covers k=kt*64.., u=ut*64.., all 40 t. 256 thr.
__global__ __launch_bounds__(256) void wprep(
    const float* __restrict__ Qw, const float* __restrict__ Bt,
    _Float16* __restrict__ W)
{
  __shared__ _Float16 ldsQ[64 * 512];  // [dk][du*8+q], 64 KB
  __shared__ float ldsB[TS * 8];
  const int tid = threadIdx.x;
  const int kt = blockIdx.x;   // 0..31
  const int ut = blockIdx.y;   // 0..15
  for (int i = tid; i < TS * 8; i += 256) ldsB[i] = Bt[i];
  const float* qb = Qw + (size_t)(kt * 64) * 8192 + ut * 512;
#pragma unroll
  for (int i = 0; i < 32; ++i) {
    int s = i * 256 + tid;          // 0..8191
    int dk = s >> 7, c4 = s & 127;  // row, float4-col
    float4 v = *(const float4*)(qb + (size_t)dk * 8192 + c4 * 4);
    _Float16* d = &ldsQ[dk * 512 + c4 * 4];
    d[0] = (_Float16)v.x; d[1] = (_Float16)v.y;
    d[2] = (_Float16)v.z; d[3] = (_Float16)v.w;
  }
  __syncthreads();
  const int w = tid >> 6, lane = tid & 63;
  const int dur = lane >> 3, ko = lane & 7;
#pragma unroll 1
  for (int sp = 0; sp < 2; ++sp) {
    const int stripe = w * 2 + sp;
    const int du = stripe * 8 + dur;
    float Q[8][8];
#pragma unroll
    for (int j = 0; j < 8; ++j)
#pragma unroll
      for (int q = 0; q < 8; ++q)
        Q[j][q] = (float)ldsQ[(ko * 8 + j) * 512 + du * 8 + q];
    const size_t obase =
        (size_t)stripe * 1024 + ((dur * 128 + ko * 16) ^ (dur << 4));
#pragma unroll 1
    for (int t = 0; t < TS; ++t) {
      float b[8];
#pragma unroll
      for (int q = 0; q < 8; ++q) b[q] = ldsB[t * 8 + q];
      half8 v;
#pragma unroll
      for (int j = 0; j < 8; ++j) {
        float s = 0.f;
#pragma unroll
        for (int q = 0; q < 8; ++q) s += Q[j][q] * b[q];
        v[j] = (_Float16)s;
      }
      size_t tile = ((size_t)t * 16 + ut) * 32 + kt;
      *(half8*)((char*)W + tile * 8192 + obase) = v;
    }
  }
}

// ---------------- h0 fp32 -> tiled f16 --------------------------------------
__global__ __launch_bounds__(256) void hinit(const float* __restrict__ h0,
                                             _Float16* __restrict__ hb) {
  int g = blockIdx.x * 256 + threadIdx.x;   // 262144 total, 16B each
  int lane = g & 63;
  int sg = g >> 6;                          // (bt*16+kt)*8 + stripe
  int stripe = sg & 7;
  int rest = sg >> 3;
  int kt = rest & 15, bt = rest >> 4;
  int dur = lane >> 3, ko = lane & 7;
  int b = bt * 64 + stripe * 8 + dur;
  int k = kt * 64 + ko * 8;
  float4 v0 = *(const float4*)(h0 + (size_t)b * NU + k);
  float4 v1 = *(const float4*)(h0 + (size_t)b * NU + k + 4);
  half8 h;
  h[0] = (_Float16)v0.x; h[1] = (_Float16)v0.y;
  h[2] = (_Float16)v0.z; h[3] = (_Float16)v0.w;
  h[4] = (_Float16)v1.x; h[5] = (_Float16)v1.y;
  h[6] = (_Float16)v1.z; h[7] = (_Float16)v1.w;
  size_t off = ((size_t)(bt * 16 + kt)) * 8192 + stripe * 1024 +
               ((dur * 128 + ko * 16) ^ (dur << 4));
  *(half8*)((char*)hb + off) = h;
}

// ---------------- batched x-projection: pre[t][b][u] = x_t @ Wx_t + bias ----
// 128x128 tile, BK=64, grid (16,8,40). B-operand read from tiled W (linear).
__global__ __launch_bounds__(256) void xproj(
    const float* __restrict__ x, const _Float16* __restrict__ W,
    const float* __restrict__ bias, _Float16* __restrict__ pre)
{
  __shared__ _Float16 ldsA[2][128 * 64];
  __shared__ _Float16 ldsB[2][128 * 64];
  const int tid = threadIdx.x;
  const int t = blockIdx.z;
  const int b0 = blockIdx.x * 128;
  const int u0 = blockIdx.y * 128;
  const int ut0 = u0 >> 6;
  const int lane = tid & 63;
  const int wv = tid >> 6;
  const int wm = wv >> 1, wn = wv & 1;
  const int l15 = lane & 15, lk = lane >> 4;

  float4 areg[8];
  uint4 breg[4];
  const float* xb = x + (size_t)b0 * (TS * NI) + (size_t)t * NI;
  // tile base for (t, ut0, kt_tile=16): x-half of K
  const char* wtb = (const char*)W + (((size_t)t * 16 + ut0) * 32 + 16) * 8192;

  auto stage_load = [&](int kt) {
    const int k0 = kt * 64;
#pragma unroll
    for (int i = 0; i < 8; ++i) {
      int s = i * 256 + tid;
      int r = s >> 4, c4 = s & 15;
      areg[i] = *(const float4*)(xb + (size_t)r * (TS * NI) + k0 + c4 * 4);
    }
#pragma unroll
    for (int i = 0; i < 4; ++i) {
      int s = i * 256 + tid;  // 0..1023 -> byte s*16 of two tiles
      const char* src = wtb + (size_t)(s >> 9) * (32 * 8192) +
                        (size_t)kt * 8192 + (size_t)(s & 511) * 16;
      breg[i] = *(const uint4*)src;
    }
  };

  auto stage_write = [&](int buf) {
    char* pA = (char*)&ldsA[buf][0];
    char* pB = (char*)&ldsB[buf][0];
#pragma unroll
    for (int i = 0; i < 8; ++i) {
      int s = i * 256 + tid;
      int r = s >> 4, c4 = s & 15;
      half4v h;
      h[0] = (_Float16)areg[i].x; h[1] = (_Float16)areg[i].y;
      h[2] = (_Float16)areg[i].z; h[3] = (_Float16)areg[i].w;
      int off = (r * 128 + c4 * 8) ^ ((r & 7) << 4);
      *(half4v*)(pA + off) = h;
    }
#pragma unroll
    for (int i = 0; i < 4; ++i) {
      int s = i * 256 + tid;
      *(uint4*)(pB + s * 16) = breg[i];  // linear: tile bytes == LDS bytes
    }
  };

  floatx4 acc[4][4] = {};

  auto compute = [&](int buf) {
    const char* pA = (const char*)&ldsA[buf][0];
    const char* pB = (const char*)&ldsB[buf][0];
#pragma unroll
    for (int kk = 0; kk < 2; ++kk) {
      half8 af[4], bf[4];
#pragma unroll
      for (int mf = 0; mf < 4; ++mf) {
        int r = wm * 64 + mf * 16 + l15;
        int off = r * 128 + ((((kk << 2) | lk) ^ (r & 7)) << 4);
        af[mf] = *(const half8*)(pA + off);
      }
#pragma unroll
      for (int nf = 0; nf < 4; ++nf) {
        int u = wn * 64 + nf * 16 + l15;
        int off = u * 128 + ((((kk << 2) | lk) ^ (u & 7)) << 4);
        bf[nf] = *(const half8*)(pB + off);
      }
#pragma unroll
      for (int mf = 0; mf < 4; ++mf)
#pragma unroll
        for (int nf = 0; nf < 4; ++nf)
          acc[mf][nf] =
              __builtin_amdgcn_mfma_f32_16x16x32_f16(af[mf], bf[nf], acc[mf][nf], 0, 0, 0);
    }
  };

  stage_load(0);
  stage_write(0);
  __syncthreads();
#pragma unroll 1
  for (int kt = 0; kt < 16; ++kt) {
    int cur = kt & 1;
    if (kt + 1 < 16) stage_load(kt + 1);
    compute(cur);
    if (kt + 1 < 16) stage_write(cur ^ 1);
    __syncthreads();
  }

#pragma unroll
  for (int mf = 0; mf < 4; ++mf)
#pragma unroll
    for (int nf = 0; nf < 4; ++nf) {
      int u = u0 + wn * 64 + nf * 16 + l15;
      float bv = bias[u];
      int brow = b0 + wm * 64 + mf * 16 + (lk << 2);
#pragma unroll
      for (int j = 0; j < 4; ++j)
        pre[((size_t)t * NB + brow + j) * NU + u] =
            (_Float16)(acc[mf][nf][j] + bv);
    }
}

// ---------------- serial step: h_t = tanh(h_{t-1} @ Wh_t + pre_t) -----------
// 64x64 tile, K=1024 (16 kt). DMA tiles via global_load_lds, DEPTH=4 pipeline,
// counted vmcnt (12 = 3 tiles x 4 loads in flight). 512 blocks (2/CU).
__global__ __launch_bounds__(256) void serial_step(
    const _Float16* __restrict__ Wt,    // W + t*UD (tiled, this t)
    const _Float16* __restrict__ pret,  // pre + t*NB*NU (linear f16)
    const _Float16* __restrict__ hprev, // tiled
    _Float16* __restrict__ hnext,       // tiled
    float* __restrict__ outt)           // out + t*NU, row stride TS*NU
{
  __shared__ uint4 lds4[4][1024];       // 4 bufs x (A 8KB | B 8KB)
  const int tid = threadIdx.x;
  const int bid = blockIdx.x;
  const int bt = bid & 31, ut = bid >> 5;
  const int lane = tid & 63, w = tid >> 6;
  const int wm = w >> 1, wn = w & 1;
  const int l15 = lane & 15, lk = lane >> 4;
  const int b0 = bt * 64, u0 = ut * 64;

  // prefetch epilogue operand pre (independent loads; overlap with pipeline)
  _Float16 pr[2][2][4];
#pragma unroll
  for (int mf = 0; mf < 2; ++mf)
#pragma unroll
    for (int nf = 0; nf < 2; ++nf)
#pragma unroll
      for (int j = 0; j < 4; ++j)
        pr[mf][nf][j] = pret[
            (size_t)(b0 + wm * 32 + mf * 16 + (lk << 2) + j) * NU +
            (u0 + wn * 32 + nf * 16 + l15)];

  const char* Asrc = (const char*)hprev + (size_t)bt * 16 * 8192;
  const char* Bsrc = (const char*)Wt + (size_t)ut * 32 * 8192;

  auto issue_tile = [&](int kt) {
    char* ld = (char*)&lds4[kt & 3][0];
    const char* ga = Asrc + (size_t)kt * 8192 + w * 2048 + lane * 16;
    const char* gb = Bsrc + (size_t)kt * 8192 + w * 2048 + lane * 16;
    char* la = ld + w * 2048;
    char* lb = ld + 8192 + w * 2048;
    gload16(ga, la);
    gload16(ga + 1024, la + 1024);
    gload16(gb, lb);
    gload16(gb + 1024, lb + 1024);
  };

  floatx4 acc[2][2] = {};

  auto compute = [&](int d) {
    const char* pA = (const char*)&lds4[d][0];
    const char* pB = pA + 8192;
#pragma unroll
    for (int kk = 0; kk < 2; ++kk) {
      half8 af[2], bf[2];
#pragma unroll
      for (int mf = 0; mf < 2; ++mf) {
        int r = wm * 32 + mf * 16 + l15;
        int off = r * 128 + ((((kk << 2) | lk) ^ (r & 7)) << 4);
        af[mf] = *(const half8*)(pA + off);
      }
#pragma unroll
      for (int nf = 0; nf < 2; ++nf) {
        int u = wn * 32 + nf * 16 + l15;
        int off = u * 128 + ((((kk << 2) | lk) ^ (u & 7)) << 4);
        bf[nf] = *(const half8*)(pB + off);
      }
#pragma unroll
      for (int mf = 0; mf < 2; ++mf)
#pragma unroll
        for (int nf = 0; nf < 2; ++nf)
          acc[mf][nf] =
              __builtin_amdgcn_mfma_f32_16x16x32_f16(af[mf], bf[nf], acc[mf][nf], 0, 0, 0);
    }
  };

  issue_tile(0);
  issue_tile(1);
  issue_tile(2);
#pragma unroll 1
  for (int kt = 0; kt < 16; ++kt) {
    if (kt + 3 < 16) issue_tile(kt + 3);
    if (kt < 13)       asm volatile("s_waitcnt vmcnt(12)" ::: "memory");
    else if (kt == 13) asm volatile("s_waitcnt vmcnt(8)" ::: "memory");
    else if (kt == 14) asm volatile("s_waitcnt vmcnt(4)" ::: "memory");
    else               asm volatile("s_waitcnt vmcnt(0)" ::: "memory");
    __syncthreads();
    compute(kt & 3);
    __syncthreads();
  }

#pragma unroll
  for (int mf = 0; mf < 2; ++mf)
#pragma unroll
    for (int nf = 0; nf < 2; ++nf) {
      int u = u0 + wn * 32 + nf * 16 + l15;
      int brow = b0 + wm * 32 + mf * 16 + (lk << 2);
#pragma unroll
      for (int j = 0; j < 4; ++j) {
        int b = brow + j;
        float p = (float)pr[mf][nf][j];
        float v = tanh_fast(acc[mf][nf][j] + p);
        outt[(size_t)b * (TS * NU) + u] = v;
        size_t off = ((size_t)bt * 16 + ut) * 8192 +
                     (size_t)(((b & 63) * 128 + ((u & 63) >> 3) * 16) ^
                              ((b & 7) << 4)) + (u & 7) * 2;
        *(_Float16*)((char*)hnext + off) = (_Float16)v;
      }
    }
}

// ================= round-1 fallback path (small ws) =========================
__global__ __launch_bounds__(256) void wprep_lin(
    const float* __restrict__ Qw, const float* __restrict__ Bt,
    _Float16* __restrict__ W, int t0, int nt)
{
  __shared__ float ldsQ[32 * 257];
  __shared__ float ldsB[TS * 8];
  const int tid = threadIdx.x;
  const int k0 = blockIdx.x * 32;
  const int u0 = blockIdx.y * 32;
  for (int i = tid; i < TS * 8; i += 256) ldsB[i] = Bt[i];
  const float* qbase = Qw + (size_t)k0 * 8192 + (size_t)u0 * 8;
#pragma unroll
  for (int i = 0; i < 8; ++i) {
    int s = i * 256 + tid;
    int r = s >> 6, c4 = s & 63;
    float4 v = *(const float4*)(qbase + (size_t)r * 8192 + c4 * 4);
    float* d = &ldsQ[r * 257 + c4 * 4];
    d[0] = v.x; d[1] = v.y; d[2] = v.z; d[3] = v.w;
  }
  __syncthreads();
  const int kl = tid & 31;
  const int ug = tid >> 5;
#pragma unroll
  for (int p = 0; p < 4; ++p) {
    int uu = p * 8 + ug;
    float q[8];
#pragma unroll
    for (int j = 0; j < 8; ++j) q[j] = ldsQ[kl * 257 + uu * 8 + j];
    size_t obase = (size_t)(u0 + uu) * 2048 + k0 + kl;
    for (int tt = 0; tt < nt; ++tt) {
      const float* bt = &ldsB[(t0 + tt) * 8];
      float v = 0.f;
#pragma unroll
      for (int j = 0; j < 8; ++j) v += q[j] * bt[j];
      W[(size_t)tt * UD + obase] = (_Float16)v;
    }
  }
}

__global__ __launch_bounds__(256) void step_gemm(
    const float* __restrict__ xt, const float* __restrict__ hp, long hstride,
    const _Float16* __restrict__ Wt, const float* __restrict__ bias,
    float* __restrict__ outt)
{
  __shared__ _Float16 ldsA[2][64 * 64];
  __shared__ _Float16 ldsB[2][128 * 64];
  const int tid = threadIdx.x;
  const int b0 = blockIdx.x * 64;
  const int u0 = blockIdx.y * 128;
  const int lane = tid & 63;
  const int wv = tid >> 6;
  const int wm = wv >> 1, wn = wv & 1;
  const int l15 = lane & 15, lk = lane >> 4;

  float4 areg[4];
  uint4 breg[4];

  auto stage_load = [&](int kt) {
    const int k0 = kt * 64;
    const float* src; size_t stride; int koff;
    if (k0 < NU) { src = hp; stride = (size_t)hstride; koff = k0; }
    else { src = xt; stride = (size_t)TS * NI; koff = k0 - NU; }
#pragma unroll
    for (int i = 0; i < 4; ++i) {
      int s = i * 256 + tid;
      int r = s >> 4, c4 = s & 15;
      areg[i] = *(const float4*)(src + (size_t)(b0 + r) * stride + koff + c4 * 4);
    }
    const _Float16* wsrc = Wt + (size_t)u0 * 2048 + k0;
#pragma unroll
    for (int i = 0; i < 4; ++i) {
      int s = i * 256 + tid;
      int u = s >> 3, c8 = s & 7;
      breg[i] = *(const uint4*)(wsrc + (size_t)u * 2048 + c8 * 8);
    }
  };

  auto stage_write = [&](int buf) {
    char* pA = (char*)&ldsA[buf][0];
    char* pB = (char*)&ldsB[buf][0];
#pragma unroll
    for (int i = 0; i < 4; ++i) {
      int s = i * 256 + tid;
      int r = s >> 4, c4 = s & 15;
      half4v h;
      h[0] = (_Float16)areg[i].x; h[1] = (_Float16)areg[i].y;
      h[2] = (_Float16)areg[i].z; h[3] = (_Float16)areg[i].w;
      int off = (r * 128 + c4 * 8) ^ ((r & 7) << 4);
      *(half4v*)(pA + off) = h;
    }
#pragma unroll
    for (int i = 0; i < 4; ++i) {
      int s = i * 256 + tid;
      int u = s >> 3, c8 = s & 7;
      int off = (u * 128 + c8 * 16) ^ ((u & 7) << 4);
      *(uint4*)(pB + off) = breg[i];
    }
  };

  floatx4 acc[2][4] = {};

  auto compute = [&](int buf) {
    const char* pA = (const char*)&ldsA[buf][0];
    const char* pB = (const char*)&ldsB[buf][0];
#pragma unroll
    for (int kk = 0; kk < 2; ++kk) {
      half8 af[2], bf[4];
#pragma unroll
      for (int mf = 0; mf < 2; ++mf) {
        int r = wm * 32 + mf * 16 + l15;
        int off = r * 128 + ((((kk << 2) | lk) ^ (r & 7)) << 4);
        af[mf] = *(const half8*)(pA + off);
      }
#pragma unroll
      for (int nf = 0; nf < 4; ++nf) {
        int u = wn * 64 + nf * 16 + l15;
        int off = u * 128 + ((((kk << 2) | lk) ^ (u & 7)) << 4);
        bf[nf] = *(const half8*)(pB + off);
      }
#pragma unroll
      for (int mf = 0; mf < 2; ++mf)
#pragma unroll
        for (int nf = 0; nf < 4; ++nf)
          acc[mf][nf] =
              __builtin_amdgcn_mfma_f32_16x16x32_f16(af[mf], bf[nf], acc[mf][nf], 0, 0, 0);
    }
  };

  stage_load(0);
  stage_write(0);
  __syncthreads();
#pragma unroll 1
  for (int kt = 0; kt < 32; ++kt) {
    int cur = kt & 1;
    if (kt + 1 < 32) stage_load(kt + 1);
    compute(cur);
    if (kt + 1 < 32) stage_write(cur ^ 1);
    __syncthreads();
  }

#pragma unroll
  for (int mf = 0; mf < 2; ++mf)
#pragma unroll
    for (int nf = 0; nf < 4; ++nf) {
      int u = u0 + wn * 64 + nf * 16 + l15;
      float bv = bias[u];
      int brow = b0 + wm * 32 + mf * 16 + (lk << 2);
#pragma unroll
      for (int j = 0; j < 4; ++j) {
        float prev = acc[mf][nf][j] + bv;
        outt[(size_t)(brow + j) * (TS * NU) + u] = tanh_fast(prev);
      }
    }
}

extern "C" void kernel_launch(void* const* d_in, const int* in_sizes, int n_in,
                              void* d_out, int out_size, void* d_ws, size_t ws_size,
                              hipStream_t stream) {
  const float* x    = (const float*)d_in[0];
  const float* h0   = (const float*)d_in[1];
  const float* Qw   = (const float*)d_in[2];
  const float* bias = (const float*)d_in[3];
  const float* Bt   = (const float*)d_in[4];
  float* out = (float*)d_out;

  char* ws = (char*)d_ws;
  const size_t w_bytes   = (size_t)UD * TS * sizeof(_Float16);        // 167.8 MB
  const size_t pre_bytes = (size_t)TS * NB * NU * sizeof(_Float16);   // 167.8 MB
  const size_t h_bytes   = (size_t)2 * NB * NU * sizeof(_Float16);    // 8.4 MB
  const size_t need = w_bytes + pre_bytes + h_bytes;                  // ~344 MB

  _Float16* W = (_Float16*)ws;

  if (ws_size >= need) {
    _Float16* pre  = (_Float16*)(ws + w_bytes);
    _Float16* hbuf = (_Float16*)(ws + w_bytes + pre_bytes);
    const size_t hsz = (size_t)NB * NU;  // elems per h buffer (4 MB)

    wprep<<<dim3(32, 16), 256, 0, stream>>>(Qw, Bt, W);
    hinit<<<dim3(1024), 256, 0, stream>>>(h0, hbuf);
    xproj<<<dim3(16, 8, TS), 256, 0, stream>>>(x, W, bias, pre);

    for (int t = 0; t < TS; ++t) {
      const _Float16* hprev = hbuf + (size_t)(t & 1) * hsz;
      _Float16* hnext = hbuf + (size_t)((t + 1) & 1) * hsz;
      serial_step<<<dim3(512), 256, 0, stream>>>(
          W + (size_t)t * UD, pre + (size_t)t * NB * NU, hprev, hnext,
          out + (size_t)t * NU);
    }
  } else {
    // round-1 fallback (linear W layout)
    const bool big = ws_size >= w_bytes;
    if (big) wprep_lin<<<dim3(64, 32), 256, 0, stream>>>(Qw, Bt, W, 0, TS);
    for (int t = 0; t < TS; ++t) {
      const _Float16* Wtp;
      if (big) {
        Wtp = W + (size_t)t * UD;
      } else {
        wprep_lin<<<dim3(64, 32), 256, 0, stream>>>(Qw, Bt, W, t, 1);
        Wtp = W;
      }
      const float* hp = (t == 0) ? h0 : out + (size_t)(t - 1) * NU;
      long hstride = (t == 0) ? NU : (long)TS * NU;
      step_gemm<<<dim3(32, 8), 256, 0, stream>>>(
          x + (size_t)t * NI, hp, hstride, Wtp, bias, out + (size_t)t * NU);
    }
  }
}